// Round 5
// baseline (420.612 us; speedup 1.0000x reference)
//
#include <hip/hip_runtime.h>

// HierarchicalLTI2: 32-layer cascade of 64-dim LTI blocks, T=8192.
// Per-layer FIR truncation at J=16 taps; layer = GEMM (M=8192,N=64,K=1024)
// via implicit im2col, f16 MFMA fp32-acc. Taps built in fp32 by log-doubling.
// R5: R4's fused layer-pair kernel with corrected time alignment:
//   stage-a tile = times [t0-16, t0+16)  (win1 base = PAD+t0-32)
//   spill owned rows: orow in [16,32) -> times [t0, t0+16)
//   stage-b output  = times [t0, t0+16)  (win2 row r+jp, unchanged formula)

#define LYR 32
#define NO  64
#define TSEQ 8192
#define JT  16
#define PAD 32                    // halo of fused pair reaches t0-32
#define KD  (JT*NO)               // 1024
#define PROWS (TSEQ+PAD+8)        // 8232 (slack for 48-row tile loads)
#define PBUF ((size_t)PROWS*NO)   // 526848 elements (f16)

typedef _Float16 h16;
typedef _Float16 h16x8 __attribute__((ext_vector_type(8)));
typedef float    f32x4 __attribute__((ext_vector_type(4)));

// ---- prep1: zero pads (all 33 buffers), cast u + C, seed K_0 ---------------
__global__ __launch_bounds__(256) void prep1(
    const float* __restrict__ u, const float* __restrict__ B0,
    const float* __restrict__ Bl, const float* __restrict__ Cst,
    h16* __restrict__ pall, h16* __restrict__ ccast, float* __restrict__ kf32)
{
    int idx = blockIdx.x*256 + threadIdx.x;
    const int n_pad0 = PAD*NO;           // 2048
    const int n_u    = TSEQ*NO;          // 524288
    const int n_c    = LYR*NO*NO;        // 131072
    const int n_k    = LYR*NO*NO;        // 131072
    const int n_zp   = 32*PAD*NO;        // 65536 (pads of buffers 1..32)
    int total = n_pad0 + n_u + n_c + n_k + n_zp;
    for (; idx < total; idx += gridDim.x*256) {
        int e = idx;
        if (e < n_pad0) { pall[e] = (h16)0.f; continue; }
        e -= n_pad0;
        if (e < n_u) { pall[n_pad0 + e] = (h16)u[e]; continue; }
        e -= n_u;
        if (e < n_c) { ccast[e] = (h16)Cst[e]; continue; }
        e -= n_c;
        if (e < n_k) {
            int i = e >> 12;
            int r = e & 4095;
            kf32[((size_t)i*JT)*4096 + r] = (i == 0) ? B0[r] : Bl[e - 4096];
            continue;
        }
        e -= n_k;
        int b = e >> 11;                 // 0..31 -> buffer b+1, pad 2048 elems
        int off = e & 2047;
        pall[(size_t)(b+1)*PBUF + off] = (h16)0.f;
    }
}

// ---- build_step: K_{h+q} = A^h * K_q ; A^{2h} = A^h * A^h (s=0..3) ---------
__global__ __launch_bounds__(256) void build_step(
    const float* __restrict__ A_stack, float* __restrict__ kf32,
    float* __restrict__ apow, int s)
{
    int h = 1 << s;
    int extra = (s < 3) ? 1 : 0;
    int slots = h + extra;
    int layer = blockIdx.x / slots;
    int q     = blockIdx.x % slots;
    const float* X = (s == 0) ? (A_stack + (size_t)layer*4096)
                              : (apow + ((size_t)layer*4 + (s-1))*4096);
    const float* Yop;
    float* Z;
    if (q < h) { Yop = kf32 + ((size_t)layer*JT + q)*4096;
                 Z   = kf32 + ((size_t)layer*JT + h + q)*4096; }
    else       { Yop = X;
                 Z   = apow + ((size_t)layer*4 + s)*4096; }

    __shared__ float lx[64*68];
    __shared__ float ly[64*68];
    int tid = threadIdx.x;
    for (int e = tid; e < 4096; e += 256) {
        int r = e >> 6, c = e & 63;
        lx[r*68 + c] = X[e];
        ly[r*68 + c] = Yop[e];
    }
    __syncthreads();
    int r0 = (tid >> 4) << 2;
    int c0 = (tid & 15) << 2;
    float acc[4][4] = {};
    for (int k = 0; k < 64; k++) {
        float a0 = lx[(r0+0)*68 + k];
        float a1 = lx[(r0+1)*68 + k];
        float a2 = lx[(r0+2)*68 + k];
        float a3 = lx[(r0+3)*68 + k];
        f32x4 bv = *(const f32x4*)&ly[k*68 + c0];
        #pragma unroll
        for (int j = 0; j < 4; j++) {
            acc[0][j] += a0*bv[j]; acc[1][j] += a1*bv[j];
            acc[2][j] += a2*bv[j]; acc[3][j] += a3*bv[j];
        }
    }
    #pragma unroll
    for (int i2 = 0; i2 < 4; i2++) {
        f32x4 o; o[0]=acc[i2][0]; o[1]=acc[i2][1]; o[2]=acc[i2][2]; o[3]=acc[i2][3];
        *(f32x4*)&Z[(size_t)(r0+i2)*64 + c0] = o;
    }
}

// ---- castK: Kf32[i][j][n][m] -> f16 KbufT[i][n][(15-j)*64+m] ---------------
__global__ __launch_bounds__(256) void castK(const float* __restrict__ kf32,
                                             h16* __restrict__ kt)
{
    int idx = blockIdx.x*256 + threadIdx.x;
    const int total = LYR*NO*KD;     // 2,097,152
    for (; idx < total; idx += gridDim.x*256) {
        int i   = idx >> 16;
        int rem = idx & 65535;
        int n   = rem >> 10;
        int kap = rem & 1023;
        int jp  = kap >> 6, m = kap & 63;
        int j   = JT-1-jp;
        kt[idx] = (h16)kf32[(((size_t)i*JT + j)*64 + n)*64 + m];
    }
}

// ---- stage_pair: two fused layers; grid 512 x 16-row output tiles ----------
// Stage-a computes times [t0-16, t0+16) of layer 2p into LDS (win2); owned
// times [t0, t0+16) spilled to pmid for y_final. Stage-b computes times
// [t0, t0+16) of layer 2p+1. K=1024 split 4 waves x 256.
__global__ __launch_bounds__(256, 2) void stage_pair(
    const h16* __restrict__ pin, h16* __restrict__ pmid,
    h16* __restrict__ pout, const h16* __restrict__ kbA,
    const h16* __restrict__ kbB)
{
    __shared__ __align__(16) char smraw[4608 + 2*32*68*4];  // 22,016 B
    h16*   win2 = (h16*)smraw;                  // 32 x 72 h16
    float* red  = (float*)(smraw + 4608);       // 2 x 32x68 f32
    h16*   win1 = (h16*)(smraw + 4608);         // 48 x 72 h16 (aliases red)
    int tid = threadIdx.x;
    size_t t0 = (size_t)blockIdx.x * 16;
    // win1[rr] = x_{t0-32+rr}: load from padded row PAD+t0-32 (>= 0 always)
    const h16* psrc = pin + (PAD + t0 - 32)*64;
    for (int e = tid; e < 48*8; e += 256) {
        int rr = e >> 3, cc = e & 7;
        *(int4*)&win1[rr*72 + cc*8] = *(const int4*)&psrc[(size_t)rr*64 + cc*8];
    }
    __syncthreads();
    int wv = tid >> 6, lane = tid & 63, r = lane & 15, q = lane >> 4;

    // ---------------- stage a: output time t0-16+mm, mm = s*16+r ------------
    // A-row for tap-block jp = wv*4+(ls>>1): win1 row mm+jp.
    const h16* abase = &win1[(r + wv*4)*72 + q*8];
    const h16* bbase = kbA + (size_t)r*KD + wv*256 + q*8;
#define LDA(s, ls) (*(const h16x8*)(abase + ((s)*16 + ((ls)>>1))*72 + ((ls)&1)*32))
#define LDB(c, ls) (*(const h16x8*)(bbase + (c)*(16*KD) + (ls)*32))
    f32x4 acc[2][4] = {};
    {
        h16x8 a0[2], b0[4], a1[2], b1[4];
        #pragma unroll
        for (int s = 0; s < 2; s++) { a0[s]=LDA(s,0); a1[s]=LDA(s,1); }
        #pragma unroll
        for (int c = 0; c < 4; c++) { b0[c]=LDB(c,0); b1[c]=LDB(c,1); }
        #pragma unroll 1
        for (int h2 = 0; h2 < 4; h2++) {
            int pE = 2*h2 + 2; pE = pE > 7 ? 7 : pE;
            int pO = 2*h2 + 3; pO = pO > 7 ? 7 : pO;
            h16x8 ca[2], cb[4];
            #pragma unroll
            for (int s = 0; s < 2; s++) ca[s] = a0[s];
            #pragma unroll
            for (int c = 0; c < 4; c++) cb[c] = b0[c];
            #pragma unroll
            for (int s = 0; s < 2; s++) a0[s] = LDA(s, pE);
            #pragma unroll
            for (int c = 0; c < 4; c++) b0[c] = LDB(c, pE);
            #pragma unroll
            for (int s = 0; s < 2; s++)
                #pragma unroll
                for (int c = 0; c < 4; c++)
                    acc[s][c] = __builtin_amdgcn_mfma_f32_16x16x32_f16(ca[s], cb[c], acc[s][c], 0,0,0);
            #pragma unroll
            for (int s = 0; s < 2; s++) ca[s] = a1[s];
            #pragma unroll
            for (int c = 0; c < 4; c++) cb[c] = b1[c];
            #pragma unroll
            for (int s = 0; s < 2; s++) a1[s] = LDA(s, pO);
            #pragma unroll
            for (int c = 0; c < 4; c++) b1[c] = LDB(c, pO);
            #pragma unroll
            for (int s = 0; s < 2; s++)
                #pragma unroll
                for (int c = 0; c < 4; c++)
                    acc[s][c] = __builtin_amdgcn_mfma_f32_16x16x32_f16(ca[s], cb[c], acc[s][c], 0,0,0);
        }
    }
#undef LDA
#undef LDB
    // pre-issue stage-b B prefetch (independent of LDS; hides under reduction)
    const h16* bbase2 = kbB + (size_t)r*KD + wv*256 + q*8;
#define LDB3(c, ls) (*(const h16x8*)(bbase2 + (c)*(16*KD) + (ls)*32))
    h16x8 b2E[4], b2O[4];
    #pragma unroll
    for (int c = 0; c < 4; c++) { b2E[c]=LDB3(c,0); b2O[c]=LDB3(c,1); }

    __syncthreads();                 // all win1 reads done; red may overwrite
    if (wv >= 2) {
        float* myred = red + (size_t)(wv-2)*(32*68);
        #pragma unroll
        for (int s = 0; s < 2; s++)
            #pragma unroll
            for (int c = 0; c < 4; c++)
                #pragma unroll
                for (int g = 0; g < 4; g++)
                    myred[(s*16 + q*4 + g)*68 + c*16 + r] = acc[s][c][g];
    }
    __syncthreads();
    if (wv < 2) {
        float* myred = red + (size_t)wv*(32*68);
        #pragma unroll
        for (int s = 0; s < 2; s++)
            #pragma unroll
            for (int c = 0; c < 4; c++)
                #pragma unroll
                for (int g = 0; g < 4; g++)
                    myred[(s*16 + q*4 + g)*68 + c*16 + r] += acc[s][c][g];
    }
    __syncthreads();
    // combine 2 copies -> h16 into win2; spill owned times [t0,t0+16)
    {
        int orow = tid >> 3, cb2 = (tid & 7) << 3;
        f32x4 u0 = *(const f32x4*)&red[orow*68 + cb2];
        f32x4 u1 = *(const f32x4*)&red[orow*68 + cb2 + 4];
        f32x4 v0 = *(const f32x4*)&red[32*68 + orow*68 + cb2];
        f32x4 v1 = *(const f32x4*)&red[32*68 + orow*68 + cb2 + 4];
        u0 += v0; u1 += v1;
        h16 ov[8];
        #pragma unroll
        for (int j = 0; j < 4; j++) { ov[j] = (h16)u0[j]; ov[4+j] = (h16)u1[j]; }
        __syncthreads();             // all red reads complete
        *(int4*)&win2[orow*72 + cb2] = *(int4*)&ov[0];   // win2[orow]=t0-16+orow
        if (orow >= 16)
            *(int4*)&pmid[(PAD + t0 + orow - 16)*64 + cb2] = *(int4*)&ov[0];
    }
    __syncthreads();

    // ---------------- stage b: output time t0+r ------------------------------
    // A-row for tap-block jp: win2 row r+jp  (since win2[0] = time t0-16).
    const h16* abase2 = &win2[(r + wv*4)*72 + q*8];
#define LDA3(ls) (*(const h16x8*)(abase2 + (((ls)>>1))*72 + ((ls)&1)*32))
    f32x4 acc2[4] = {};
    {
        h16x8 a20 = LDA3(0), a21 = LDA3(1);
        #pragma unroll 1
        for (int h2 = 0; h2 < 4; h2++) {
            int pE = 2*h2 + 2; pE = pE > 7 ? 7 : pE;
            int pO = 2*h2 + 3; pO = pO > 7 ? 7 : pO;
            h16x8 ca = a20, cb[4];
            #pragma unroll
            for (int c = 0; c < 4; c++) cb[c] = b2E[c];
            a20 = LDA3(pE);
            #pragma unroll
            for (int c = 0; c < 4; c++) b2E[c] = LDB3(c, pE);
            #pragma unroll
            for (int c = 0; c < 4; c++)
                acc2[c] = __builtin_amdgcn_mfma_f32_16x16x32_f16(ca, cb[c], acc2[c], 0,0,0);
            ca = a21;
            #pragma unroll
            for (int c = 0; c < 4; c++) cb[c] = b2O[c];
            a21 = LDA3(pO);
            #pragma unroll
            for (int c = 0; c < 4; c++) b2O[c] = LDB3(c, pO);
            #pragma unroll
            for (int c = 0; c < 4; c++)
                acc2[c] = __builtin_amdgcn_mfma_f32_16x16x32_f16(ca, cb[c], acc2[c], 0,0,0);
        }
    }
#undef LDA3
#undef LDB3
    __syncthreads();                 // win2 reads + prior red reads complete
    if (wv >= 2) {
        float* myred = red + (size_t)(wv-2)*(32*68);
        #pragma unroll
        for (int c = 0; c < 4; c++)
            #pragma unroll
            for (int g = 0; g < 4; g++)
                myred[(q*4 + g)*68 + c*16 + r] = acc2[c][g];
    }
    __syncthreads();
    if (wv < 2) {
        float* myred = red + (size_t)wv*(32*68);
        #pragma unroll
        for (int c = 0; c < 4; c++)
            #pragma unroll
            for (int g = 0; g < 4; g++)
                myred[(q*4 + g)*68 + c*16 + r] += acc2[c][g];
    }
    __syncthreads();
    {
        int o2 = tid >> 4, c4 = (tid & 15) << 2;
        f32x4 s0 = *(const f32x4*)&red[o2*68 + c4];
        f32x4 s1 = *(const f32x4*)&red[32*68 + o2*68 + c4];
        s0 += s1;
        h16 ov[4];
        #pragma unroll
        for (int j = 0; j < 4; j++) ov[j] = (h16)s0[j];
        *(int2*)&pout[(PAD + t0 + o2)*64 + c4] = *(int2*)&ov[0];
    }
}

// ---- y_final: Y = sum_i X^(i) C_i^T, 32-row tiles, split layers 4-ways -----
__global__ __launch_bounds__(256, 2) void y_final(
    const h16* __restrict__ pall, const h16* __restrict__ ccast,
    float* __restrict__ out)
{
    __shared__ __align__(16) float red[2*32*68];
    int tid = threadIdx.x;
    size_t t0 = (size_t)blockIdx.x * 32;
    int wv = tid >> 6, lane = tid & 63, r = lane & 15, q = lane >> 4;
    const h16* abase = pall + (size_t)(wv*8 + 1)*PBUF + (PAD + t0 + r)*64 + q*8;
    const h16* bbase = ccast + (size_t)(wv*8)*4096 + (size_t)r*64 + q*8;
#define LDA2(s, ls) (*(const h16x8*)(abase + (size_t)((ls)>>1)*PBUF + (s)*(16*64) + ((ls)&1)*32))
#define LDB2(c, ls) (*(const h16x8*)(bbase + ((ls)>>1)*4096 + (c)*(16*64) + ((ls)&1)*32))
    f32x4 acc[2][4] = {};
    h16x8 a0[2], b0[4], a1[2], b1[4];
    #pragma unroll
    for (int s = 0; s < 2; s++) { a0[s]=LDA2(s,0); a1[s]=LDA2(s,1); }
    #pragma unroll
    for (int c = 0; c < 4; c++) { b0[c]=LDB2(c,0); b1[c]=LDB2(c,1); }
    #pragma unroll 1
    for (int h2 = 0; h2 < 8; h2++) {
        int pE = 2*h2 + 2; pE = pE > 15 ? 15 : pE;
        int pO = 2*h2 + 3; pO = pO > 15 ? 15 : pO;
        h16x8 ca[2], cb[4];
        #pragma unroll
        for (int s = 0; s < 2; s++) ca[s] = a0[s];
        #pragma unroll
        for (int c = 0; c < 4; c++) cb[c] = b0[c];
        #pragma unroll
        for (int s = 0; s < 2; s++) a0[s] = LDA2(s, pE);
        #pragma unroll
        for (int c = 0; c < 4; c++) b0[c] = LDB2(c, pE);
        #pragma unroll
        for (int s = 0; s < 2; s++)
            #pragma unroll
            for (int c = 0; c < 4; c++)
                acc[s][c] = __builtin_amdgcn_mfma_f32_16x16x32_f16(ca[s], cb[c], acc[s][c], 0,0,0);
        #pragma unroll
        for (int s = 0; s < 2; s++) ca[s] = a1[s];
        #pragma unroll
        for (int c = 0; c < 4; c++) cb[c] = b1[c];
        #pragma unroll
        for (int s = 0; s < 2; s++) a1[s] = LDA2(s, pO);
        #pragma unroll
        for (int c = 0; c < 4; c++) b1[c] = LDB2(c, pO);
        #pragma unroll
        for (int s = 0; s < 2; s++)
            #pragma unroll
            for (int c = 0; c < 4; c++)
                acc[s][c] = __builtin_amdgcn_mfma_f32_16x16x32_f16(ca[s], cb[c], acc[s][c], 0,0,0);
    }
#undef LDA2
#undef LDB2
    if (wv >= 2) {
        float* myred = red + (size_t)(wv-2)*(32*68);
        #pragma unroll
        for (int s = 0; s < 2; s++)
            #pragma unroll
            for (int c = 0; c < 4; c++)
                #pragma unroll
                for (int g = 0; g < 4; g++)
                    myred[(s*16 + q*4 + g)*68 + c*16 + r] = acc[s][c][g];
    }
    __syncthreads();
    if (wv < 2) {
        float* myred = red + (size_t)wv*(32*68);
        #pragma unroll
        for (int s = 0; s < 2; s++)
            #pragma unroll
            for (int c = 0; c < 4; c++)
                #pragma unroll
                for (int g = 0; g < 4; g++)
                    myred[(s*16 + q*4 + g)*68 + c*16 + r] += acc[s][c][g];
    }
    __syncthreads();
    int orow = tid >> 3, cb2 = (tid & 7) << 3;
    f32x4 u0 = *(const f32x4*)&red[orow*68 + cb2];
    f32x4 u1 = *(const f32x4*)&red[orow*68 + cb2 + 4];
    f32x4 v0 = *(const f32x4*)&red[32*68 + orow*68 + cb2];
    f32x4 v1 = *(const f32x4*)&red[32*68 + orow*68 + cb2 + 4];
    u0 += v0; u1 += v1;
    size_t obase = (t0 + orow)*64 + cb2;
    *(f32x4*)&out[obase]     = u0;
    *(f32x4*)&out[obase + 4] = u1;
}

extern "C" void kernel_launch(void* const* d_in, const int* in_sizes, int n_in,
                              void* d_out, int out_size, void* d_ws, size_t ws_size,
                              hipStream_t stream)
{
    const float* u   = (const float*)d_in[0];
    const float* Ast = (const float*)d_in[1];
    const float* B0  = (const float*)d_in[2];
    const float* Bl  = (const float*)d_in[3];
    const float* Cst = (const float*)d_in[4];
    float* out = (float*)d_out;
    (void)in_sizes; (void)n_in; (void)out_size; (void)ws_size;

    char* ws = (char*)d_ws;
    const size_t PBUF_BYTES = PBUF*sizeof(h16);            // 1,053,696
    h16*   pall  = (h16*)ws;                               // 33 buffers
    h16*   ccast = (h16*)(ws + 33*PBUF_BYTES);             // 256 KiB
    h16*   kt    = (h16*)(ws + 33*PBUF_BYTES + 262144);    // 4 MiB
    float* kf32  = (float*)(ws + 33*PBUF_BYTES + 262144 + 4194304);   // 8 MiB
    float* apow  = (float*)(ws + 33*PBUF_BYTES + 262144 + 4194304 + 8388608); // 2 MiB

    prep1<<<2048, 256, 0, stream>>>(u, B0, Bl, Cst, pall, ccast, kf32);
    for (int s = 0; s < 4; s++) {
        int h = 1 << s;
        int grid = 32*(h + (s < 3 ? 1 : 0));
        build_step<<<grid, 256, 0, stream>>>(Ast, kf32, apow, s);
    }
    castK<<<2048, 256, 0, stream>>>(kf32, kt);
    for (int p = 0; p < LYR/2; p++) {
        stage_pair<<<TSEQ/16, 256, 0, stream>>>(
            pall + (size_t)(2*p)*PBUF,          // input  = x^(2p-1) (or u)
            pall + (size_t)(2*p+1)*PBUF,        // mid    = x^(2p)
            pall + (size_t)(2*p+2)*PBUF,        // out    = x^(2p+1)
            kt + (size_t)(2*p)*NO*KD,
            kt + (size_t)(2*p+1)*NO*KD);
    }
    y_final<<<TSEQ/32, 256, 0, stream>>>(pall, ccast, out);
}